// Round 1
// baseline (147.723 us; speedup 1.0000x reference)
//
#include <hip/hip_runtime.h>
#include <math.h>

#define NG 128
#define NIN 512
#define OFF1 4194304   // 8192*512
#define OFF2 8388608   // 2*8192*512
#define OFF3 9437184   // OFF2 + 8192*128

#define INV_SQRT_2PI 0.3989422804014327f
#define INV_SQRT2    0.7071067811865476f

__device__ __forceinline__ float gelu_f(float x){
    return 0.5f*x*(1.0f + erff(x*INV_SQRT2));
}
__device__ __forceinline__ float gelu_df(float x){
    return 0.5f*(1.0f + erff(x*INV_SQRT2)) + x*INV_SQRT_2PI*expf(-0.5f*x*x);
}

// Kernel 1: per-group tv(t) and d tv/dt (depend only on t + group weights)
__global__ void k_pre(const float* __restrict__ ts,
                      const float* __restrict__ Wt,  const float* __restrict__ bt,
                      const float* __restrict__ Wt2, const float* __restrict__ bt2,
                      float* __restrict__ tv_ws, float* __restrict__ dtv_ws){
    int g = threadIdx.x;
    if (g >= NG) return;
    float t  = ts[0];
    float f1 = expf(-0.5f*logf(10000.0f));     // freqs = [1, ~0.01]
    float te0 = t, te1 = t*f1;
    float temb[4]  = { sinf(te0),  sinf(te1),     cosf(te0),     cosf(te1) };
    float dtemb[4] = { cosf(te0),  f1*cosf(te1), -sinf(te0), -f1*sinf(te1) };
    float tg[4], dg[4];
    #pragma unroll
    for (int i=0;i<4;i++){
        float a = bt[g*4+i], d = 0.0f;
        #pragma unroll
        for (int j=0;j<4;j++){
            float w = Wt[g*16+i*4+j];
            a += w*temb[j]; d += w*dtemb[j];
        }
        tg[i] = gelu_f(a);
        dg[i] = gelu_df(a)*d;
    }
    #pragma unroll
    for (int j=0;j<4;j++){
        float a = bt2[g*4+j], d = 0.0f;
        #pragma unroll
        for (int i=0;i<4;i++){
            float w = Wt2[g*16+j*4+i];
            a += w*tg[i]; d += w*dg[i];
        }
        tv_ws[g*4+j]  = a;
        dtv_ws[g*4+j] = d;
    }
}

// Kernel 2: dS/dt per (b,g), reduced to deterministic per-block partials.
// 512 blocks x 256 threads; each thread = one group, 8 batch rows.
__global__ __launch_bounds__(256) void k_dsdt(const float* __restrict__ z,
    const float* __restrict__ Wx, const float* __restrict__ bx,
    const float* __restrict__ Wf, const float* __restrict__ bf,
    const float* __restrict__ Wo, const float* __restrict__ bo,
    const float* __restrict__ tv_ws, const float* __restrict__ dtv_ws,
    float* __restrict__ partial){
    const int tid  = threadIdx.x;
    const int gidx = tid & 127;
    const int lb   = tid >> 7;
    float wx[16], wf[16];
    #pragma unroll
    for (int i=0;i<4;i++){
        float4 a4 = ((const float4*)(Wx + gidx*16))[i];
        wx[i*4+0]=a4.x; wx[i*4+1]=a4.y; wx[i*4+2]=a4.z; wx[i*4+3]=a4.w;
        float4 b4 = ((const float4*)(Wf + gidx*16))[i];
        wf[i*4+0]=b4.x; wf[i*4+1]=b4.y; wf[i*4+2]=b4.z; wf[i*4+3]=b4.w;
    }
    float4 t4;
    t4 = ((const float4*)bx)[gidx];     float bxA[4]={t4.x,t4.y,t4.z,t4.w};
    t4 = ((const float4*)bf)[gidx];     float bfA[4]={t4.x,t4.y,t4.z,t4.w};
    t4 = ((const float4*)Wo)[gidx];     float w3[4] ={t4.x,t4.y,t4.z,t4.w};
    t4 = ((const float4*)tv_ws)[gidx];  float tvA[4]={t4.x,t4.y,t4.z,t4.w};
    t4 = ((const float4*)dtv_ws)[gidx]; float dtvA[4]={t4.x,t4.y,t4.z,t4.w};
    float bo0 = bo[gidx];

    float acc = 0.0f;
    const int b0 = blockIdx.x*16 + lb;
    #pragma unroll
    for (int k=0;k<8;k++){
        int b = b0 + 2*k;
        float4 zv = *((const float4*)(z + b*NIN + gidx*4));
        float zz[4]={zv.x,zv.y,zv.z,zv.w};
        float u1[4];
        #pragma unroll
        for (int i=0;i<4;i++){
            float a = bxA[i] + wx[i*4]*zz[0]+wx[i*4+1]*zz[1]+wx[i*4+2]*zz[2]+wx[i*4+3]*zz[3];
            float x = tanhf(a);
            u1[i] = x + tvA[i];
        }
        float hp[4];
        float a3 = bo0;
        #pragma unroll
        for (int i=0;i<4;i++){
            float a = bfA[i] + wf[i*4]*u1[0]+wf[i*4+1]*u1[1]+wf[i*4+2]*u1[2]+wf[i*4+3]*u1[3];
            float h = tanhf(a);
            hp[i] = 1.0f - h*h;
            a3 += w3[i]*h;
        }
        float S = tanhf(a3), sp = 1.0f - S*S;
        float q[4]={0.f,0.f,0.f,0.f};
        #pragma unroll
        for (int i=0;i<4;i++){
            float vi = sp*w3[i]*hp[i];
            #pragma unroll
            for (int j=0;j<4;j++) q[j] += vi*wf[i*4+j];
        }
        acc += q[0]*dtvA[0]+q[1]*dtvA[1]+q[2]*dtvA[2]+q[3]*dtvA[3];
    }
    __shared__ float sred[256];
    sred[tid] = acc;
    __syncthreads();
    if (tid < 128) partial[tid*512 + blockIdx.x] = sred[tid] + sred[tid+128];
}

// Kernel 3: reduce 512 partials per group -> dSdt_sum[g]
__global__ void k_red(const float* __restrict__ partial, float* __restrict__ dsum){
    int g = blockIdx.x;
    int t = threadIdx.x;
    float a = 0.0f;
    for (int i=t;i<512;i+=64) a += partial[g*512+i];
    #pragma unroll
    for (int o=32;o>0;o>>=1) a += __shfl_down(a, o);
    if (t==0) dsum[g] = a;
}

// Kernel 4: everything else. 4096 blocks x 256 threads; thread = (b, group).
__global__ __launch_bounds__(256) void k_main(const float* __restrict__ z,
    const float* __restrict__ mup, const float* __restrict__ sigp,
    const float* __restrict__ Wx, const float* __restrict__ bx,
    const float* __restrict__ Wf, const float* __restrict__ bf,
    const float* __restrict__ Wo, const float* __restrict__ bo,
    const float* __restrict__ betap, const float* __restrict__ tv_ws,
    const float* __restrict__ dsum, float* __restrict__ out){
    const int tid  = threadIdx.x;
    const int gidx = tid & 127;
    const int b    = blockIdx.x*2 + (tid>>7);

    const float mu = mup[0], sigma = sigp[0];
    const float sig2   = sigma*sigma + 1e-5f;
    const float dlp    = -1.0f/sig2;
    const float inv_s4 = 1.0f/(sigma*sigma*sigma*sigma + 1e-5f);
    const float phi_b  = 0.5f*(1.0f+erff((10.0f-mu)/sigma*INV_SQRT2));
    const float phi_a  = 0.5f*(1.0f+erff((-10.0f-mu)/sigma*INV_SQRT2));
    const float invZ   = 1.0f/(phi_b-phi_a);

    float wx[16], wf[16];
    #pragma unroll
    for (int i=0;i<4;i++){
        float4 a4 = ((const float4*)(Wx + gidx*16))[i];
        wx[i*4+0]=a4.x; wx[i*4+1]=a4.y; wx[i*4+2]=a4.z; wx[i*4+3]=a4.w;
        float4 b4 = ((const float4*)(Wf + gidx*16))[i];
        wf[i*4+0]=b4.x; wf[i*4+1]=b4.y; wf[i*4+2]=b4.z; wf[i*4+3]=b4.w;
    }
    float4 t4;
    t4 = ((const float4*)bx)[gidx];    float bxA[4]={t4.x,t4.y,t4.z,t4.w};
    t4 = ((const float4*)bf)[gidx];    float bfA[4]={t4.x,t4.y,t4.z,t4.w};
    t4 = ((const float4*)Wo)[gidx];    float w3[4] ={t4.x,t4.y,t4.z,t4.w};
    t4 = ((const float4*)tv_ws)[gidx]; float tvA[4]={t4.x,t4.y,t4.z,t4.w};
    const float bo0    = bo[gidx];
    const float bb     = betap[gidx];
    const float dS_sum = dsum[gidx];

    float4 zv = *((const float4*)(z + b*NIN + gidx*4));
    float zz[4]={zv.x,zv.y,zv.z,zv.w};

    // forward
    float x[4], xp[4], u1[4];
    #pragma unroll
    for (int i=0;i<4;i++){
        float a = bxA[i] + wx[i*4]*zz[0]+wx[i*4+1]*zz[1]+wx[i*4+2]*zz[2]+wx[i*4+3]*zz[3];
        x[i] = tanhf(a); xp[i] = 1.0f - x[i]*x[i];
        u1[i] = x[i] + tvA[i];
    }
    float h[4], hp[4];
    float a3 = bo0;
    #pragma unroll
    for (int i=0;i<4;i++){
        float a = bfA[i] + wf[i*4]*u1[0]+wf[i*4+1]*u1[1]+wf[i*4+2]*u1[2]+wf[i*4+3]*u1[3];
        h[i] = tanhf(a); hp[i] = 1.0f - h[i]*h[i];
        a3 += w3[i]*h[i];
    }
    float S = tanhf(a3), sp = 1.0f - S*S;

    // B[i,n] = sum_k Wf[i,k] * xp_k * Wx[k,n]
    float Bm[16];
    #pragma unroll
    for (int i=0;i<4;i++){
        #pragma unroll
        for (int n=0;n<4;n++){
            float s = 0.0f;
            #pragma unroll
            for (int k=0;k<4;k++) s += wf[i*4+k]*xp[k]*wx[k*4+n];
            Bm[i*4+n]=s;
        }
    }
    float w3hp[4], v[4];
    #pragma unroll
    for (int i=0;i<4;i++){ w3hp[i]=w3[i]*hp[i]; v[i]=sp*w3hp[i]; }
    float q[4]={0.f,0.f,0.f,0.f};
    #pragma unroll
    for (int i=0;i<4;i++){
        #pragma unroll
        for (int j=0;j<4;j++) q[j] += v[i]*wf[i*4+j];
    }
    float c[4];
    #pragma unroll
    for (int n=0;n<4;n++){
        float s=0.0f;
        #pragma unroll
        for (int i=0;i<4;i++) s += w3hp[i]*Bm[i*4+n];
        c[n]=s;
    }
    const float alpha = -2.0f*S*sp;
    float bet[4], gam[4];
    #pragma unroll
    for (int i=0;i<4;i++){ bet[i] = -2.0f*h[i]*v[i]; gam[i] = -2.0f*x[i]*xp[i]*q[i]; }

    // rho / nlp / dpp
    float rho[4], nlp[4], dpp[4];
    #pragma unroll
    for (int j=0;j<4;j++){
        float zj = zz[j];
        float xs = zj > 10.0f ? zj+100.0f : zj;
        xs = xs < -10.0f ? xs-100.0f : xs;
        float xn = (xs-mu)/sigma;
        float dens = expf(-0.5f*xn*xn)*INV_SQRT_2PI;
        dens = (xn > 10.0f || xn < -10.0f) ? 0.0f : dens;
        rho[j] = dens*invZ + 1e-10f;
        nlp[j] = -(zj-mu)/sig2;
        float d = zj-mu;
        dpp[j] = (d*d - sigma*sigma)*inv_s4;
    }
    float u_val = S - bb*logf(rho[0]*rho[1]*rho[2]*rho[3]);

    // contractions with H = alpha c c^T + sum_i bet_i B_i B_i^T + sum_k gam_k A_k A_k^T
    float rc=0.0f, scs=0.0f;
    #pragma unroll
    for (int j=0;j<4;j++){ rc += rho[j]*c[j]; scs += c[j]; }
    float rB[4], sB[4], rA[4], sA[4];
    #pragma unroll
    for (int i=0;i<4;i++){
        float r=0.0f, s=0.0f, r2=0.0f, s2=0.0f;
        #pragma unroll
        for (int j=0;j<4;j++){
            r  += rho[j]*Bm[i*4+j]; s  += Bm[i*4+j];
            r2 += rho[j]*wx[i*4+j]; s2 += wx[i*4+j];
        }
        rB[i]=r; sB[i]=s; rA[i]=r2; sA[i]=s2;
    }

    float pde[4], uz[4], uzz[4];
    #pragma unroll
    for (int k=0;k<4;k++){
        float corr = alpha*rc*c[k];
        float hsum = alpha*scs*c[k];
        #pragma unroll
        for (int i=0;i<4;i++){
            corr += bet[i]*rB[i]*Bm[i*4+k];
            hsum += bet[i]*sB[i]*Bm[i*4+k];
            corr += gam[i]*rA[i]*wx[i*4+k];
            hsum += gam[i]*sA[i]*wx[i*4+k];
        }
        float uzk = sp*c[k] - bb*nlp[k];
        float utk = dS_sum + bb*corr/(rho[k]+1e-5f);
        uz[k]  = uzk;
        uzz[k] = hsum - bb*dlp;
        pde[k] = utk + 0.5f*uzk*uzk + 0.125f*bb*bb*(nlp[k]*nlp[k] - 2.0f*dpp[k]);
    }

    const int base = b*NIN + gidx*4;
    *((float4*)(out + base))        = make_float4(pde[0],pde[1],pde[2],pde[3]);
    *((float4*)(out + OFF1 + base)) = make_float4(uz[0],uz[1],uz[2],uz[3]);
    out[OFF2 + b*NG + gidx] = u_val;
    *((float4*)(out + OFF3 + base)) = make_float4(uzz[0],uzz[1],uzz[2],uzz[3]);
}

extern "C" void kernel_launch(void* const* d_in, const int* in_sizes, int n_in,
                              void* d_out, int out_size, void* d_ws, size_t ws_size,
                              hipStream_t stream){
    (void)in_sizes; (void)n_in; (void)out_size; (void)ws_size;
    const float* z     = (const float*)d_in[0];
    const float* ts    = (const float*)d_in[1];
    const float* mu    = (const float*)d_in[2];
    const float* sigma = (const float*)d_in[3];
    const float* Wx    = (const float*)d_in[4];
    const float* bx    = (const float*)d_in[5];
    const float* Wt    = (const float*)d_in[6];
    const float* bt    = (const float*)d_in[7];
    const float* Wt2   = (const float*)d_in[8];
    const float* bt2   = (const float*)d_in[9];
    const float* Wf    = (const float*)d_in[10];
    const float* bf    = (const float*)d_in[11];
    const float* Wo    = (const float*)d_in[12];
    const float* bo    = (const float*)d_in[13];
    const float* beta  = (const float*)d_in[14];
    float* out = (float*)d_out;

    float* ws      = (float*)d_ws;
    float* tv_ws   = ws;            // 512
    float* dtv_ws  = ws + 512;      // 512
    float* dsum    = ws + 1024;     // 128
    float* partial = ws + 1152;     // 512*128 = 65536

    k_pre <<<1,   128, 0, stream>>>(ts, Wt, bt, Wt2, bt2, tv_ws, dtv_ws);
    k_dsdt<<<512, 256, 0, stream>>>(z, Wx, bx, Wf, bf, Wo, bo, tv_ws, dtv_ws, partial);
    k_red <<<128,  64, 0, stream>>>(partial, dsum);
    k_main<<<4096,256, 0, stream>>>(z, mu, sigma, Wx, bx, Wf, bf, Wo, bo, beta, tv_ws, dsum, out);
}

// Round 2
// 131.006 us; speedup vs baseline: 1.1276x; 1.1276x over previous
//
#include <hip/hip_runtime.h>
#include <math.h>

#define NG 128
#define NIN 512
#define OFF1 4194304   // 8192*512
#define OFF2 8388608   // 2*8192*512
#define OFF3 9437184   // OFF2 + 8192*128

#define INV_SQRT_2PI 0.3989422804014327f
#define INV_SQRT2    0.7071067811865476f

// fast tanh: 1 - 2/(e^{2x}+1). v_exp_f32 + v_rcp_f32, ~2ulp.
// Saturates correctly: x->+inf => exp->inf => rcp->0 => 1; x->-inf => -1.
__device__ __forceinline__ float ftanh(float x){
    float e = __expf(2.0f*x);
    float r = __builtin_amdgcn_rcpf(e + 1.0f);
    return 1.0f - 2.0f*r;
}
__device__ __forceinline__ float frcp(float x){ return __builtin_amdgcn_rcpf(x); }

__device__ __forceinline__ float gelu_f(float x){
    return 0.5f*x*(1.0f + erff(x*INV_SQRT2));
}
__device__ __forceinline__ float gelu_df(float x){
    return 0.5f*(1.0f + erff(x*INV_SQRT2)) + x*INV_SQRT_2PI*expf(-0.5f*x*x);
}

// Kernel 1: per-group tv(t), d tv/dt; plus truncnorm scalar constants (thread 0).
__global__ void k_pre(const float* __restrict__ ts,
                      const float* __restrict__ mup, const float* __restrict__ sigp,
                      const float* __restrict__ Wt,  const float* __restrict__ bt,
                      const float* __restrict__ Wt2, const float* __restrict__ bt2,
                      float* __restrict__ tv_ws, float* __restrict__ dtv_ws,
                      float* __restrict__ consts){
    int g = threadIdx.x;
    if (g == 0){
        float mu = mup[0], sigma = sigp[0];
        float sig2   = sigma*sigma + 1e-5f;
        float phi_b  = 0.5f*(1.0f+erff((10.0f-mu)/sigma*INV_SQRT2));
        float phi_a  = 0.5f*(1.0f+erff((-10.0f-mu)/sigma*INV_SQRT2));
        consts[0] = sig2;
        consts[1] = -1.0f/sig2;                                    // dlp
        consts[2] = 1.0f/(sigma*sigma*sigma*sigma + 1e-5f);        // inv_s4
        consts[3] = 1.0f/(phi_b-phi_a);                            // invZ
        consts[4] = mu;
        consts[5] = 1.0f/sigma;
        consts[6] = sigma;
    }
    if (g >= NG) return;
    float t  = ts[0];
    float f1 = expf(-0.5f*logf(10000.0f));     // freqs = [1, 0.01]
    float te0 = t, te1 = t*f1;
    float temb[4]  = { sinf(te0),  sinf(te1),     cosf(te0),     cosf(te1) };
    float dtemb[4] = { cosf(te0),  f1*cosf(te1), -sinf(te0), -f1*sinf(te1) };
    float tg[4], dg[4];
    #pragma unroll
    for (int i=0;i<4;i++){
        float a = bt[g*4+i], d = 0.0f;
        #pragma unroll
        for (int j=0;j<4;j++){
            float w = Wt[g*16+i*4+j];
            a += w*temb[j]; d += w*dtemb[j];
        }
        tg[i] = gelu_f(a);
        dg[i] = gelu_df(a)*d;
    }
    #pragma unroll
    for (int j=0;j<4;j++){
        float a = bt2[g*4+j], d = 0.0f;
        #pragma unroll
        for (int i=0;i<4;i++){
            float w = Wt2[g*16+j*4+i];
            a += w*tg[i]; d += w*dg[i];
        }
        tv_ws[g*4+j]  = a;
        dtv_ws[g*4+j] = d;
    }
}

// Kernel 2: dS/dt partials. 2048 blocks x 256 threads; thread = 1 group x 2 rows
// (unrolled for ILP). 8192 waves = 32 waves/CU queued (fix for round-1's 8).
__global__ __launch_bounds__(256) void k_dsdt(const float* __restrict__ z,
    const float* __restrict__ Wx, const float* __restrict__ bx,
    const float* __restrict__ Wf, const float* __restrict__ bf,
    const float* __restrict__ Wo, const float* __restrict__ bo,
    const float* __restrict__ tv_ws, const float* __restrict__ dtv_ws,
    float* __restrict__ partial){
    const int tid  = threadIdx.x;
    const int gidx = tid & 127;
    const int lb   = tid >> 7;
    float wx[16], wf[16];
    #pragma unroll
    for (int i=0;i<4;i++){
        float4 a4 = ((const float4*)(Wx + gidx*16))[i];
        wx[i*4+0]=a4.x; wx[i*4+1]=a4.y; wx[i*4+2]=a4.z; wx[i*4+3]=a4.w;
        float4 b4 = ((const float4*)(Wf + gidx*16))[i];
        wf[i*4+0]=b4.x; wf[i*4+1]=b4.y; wf[i*4+2]=b4.z; wf[i*4+3]=b4.w;
    }
    float4 t4;
    t4 = ((const float4*)bx)[gidx];     float bxA[4]={t4.x,t4.y,t4.z,t4.w};
    t4 = ((const float4*)bf)[gidx];     float bfA[4]={t4.x,t4.y,t4.z,t4.w};
    t4 = ((const float4*)Wo)[gidx];     float w3[4] ={t4.x,t4.y,t4.z,t4.w};
    t4 = ((const float4*)tv_ws)[gidx];  float tvA[4]={t4.x,t4.y,t4.z,t4.w};
    t4 = ((const float4*)dtv_ws)[gidx]; float dtvA[4]={t4.x,t4.y,t4.z,t4.w};
    float bo0 = bo[gidx];

    float acc = 0.0f;
    const int b0 = blockIdx.x*4 + lb;
    #pragma unroll
    for (int k=0;k<2;k++){
        int b = b0 + 2*k;
        float4 zv = *((const float4*)(z + b*NIN + gidx*4));
        float zz[4]={zv.x,zv.y,zv.z,zv.w};
        float u1[4];
        #pragma unroll
        for (int i=0;i<4;i++){
            float a = bxA[i] + wx[i*4]*zz[0]+wx[i*4+1]*zz[1]+wx[i*4+2]*zz[2]+wx[i*4+3]*zz[3];
            u1[i] = ftanh(a) + tvA[i];
        }
        float hp[4];
        float a3 = bo0;
        #pragma unroll
        for (int i=0;i<4;i++){
            float a = bfA[i] + wf[i*4]*u1[0]+wf[i*4+1]*u1[1]+wf[i*4+2]*u1[2]+wf[i*4+3]*u1[3];
            float h = ftanh(a);
            hp[i] = 1.0f - h*h;
            a3 += w3[i]*h;
        }
        float S = ftanh(a3), sp = 1.0f - S*S;
        float q[4]={0.f,0.f,0.f,0.f};
        #pragma unroll
        for (int i=0;i<4;i++){
            float vi = sp*w3[i]*hp[i];
            #pragma unroll
            for (int j=0;j<4;j++) q[j] += vi*wf[i*4+j];
        }
        acc += q[0]*dtvA[0]+q[1]*dtvA[1]+q[2]*dtvA[2]+q[3]*dtvA[3];
    }
    __shared__ float sred[256];
    sred[tid] = acc;
    __syncthreads();
    if (tid < 128) partial[blockIdx.x*128 + tid] = sred[tid] + sred[tid+128];
}

// Kernel 3: reduce 2048 partials per group -> dSdt_sum[g]. 128 blocks x 256.
__global__ __launch_bounds__(256) void k_red(const float* __restrict__ partial,
                                             float* __restrict__ dsum){
    int g = blockIdx.x;
    int tid = threadIdx.x;
    float a = 0.0f;
    for (int i=tid;i<2048;i+=256) a += partial[i*128+g];
    __shared__ float s[256];
    s[tid] = a;
    __syncthreads();
    if (tid < 64){
        a = s[tid] + s[tid+64] + s[tid+128] + s[tid+192];
        #pragma unroll
        for (int o=32;o>0;o>>=1) a += __shfl_down(a, o);
        if (tid==0) dsum[g] = a;
    }
}

// Kernel 4: everything else. 4096 blocks x 256 threads; thread = (b, group).
__global__ __launch_bounds__(256) void k_main(const float* __restrict__ z,
    const float* __restrict__ Wx, const float* __restrict__ bx,
    const float* __restrict__ Wf, const float* __restrict__ bf,
    const float* __restrict__ Wo, const float* __restrict__ bo,
    const float* __restrict__ betap, const float* __restrict__ tv_ws,
    const float* __restrict__ consts,
    const float* __restrict__ dsum, float* __restrict__ out){
    const int tid  = threadIdx.x;
    const int gidx = tid & 127;
    const int b    = blockIdx.x*2 + (tid>>7);

    const float sig2    = consts[0];
    const float dlp     = consts[1];
    const float inv_s4  = consts[2];
    const float invZ    = consts[3];
    const float mu      = consts[4];
    const float inv_sig = consts[5];
    const float sigma   = consts[6];
    const float inv_sig2 = frcp(sig2);

    float wx[16], wf[16];
    #pragma unroll
    for (int i=0;i<4;i++){
        float4 a4 = ((const float4*)(Wx + gidx*16))[i];
        wx[i*4+0]=a4.x; wx[i*4+1]=a4.y; wx[i*4+2]=a4.z; wx[i*4+3]=a4.w;
        float4 b4 = ((const float4*)(Wf + gidx*16))[i];
        wf[i*4+0]=b4.x; wf[i*4+1]=b4.y; wf[i*4+2]=b4.z; wf[i*4+3]=b4.w;
    }
    float4 t4;
    t4 = ((const float4*)bx)[gidx];    float bxA[4]={t4.x,t4.y,t4.z,t4.w};
    t4 = ((const float4*)bf)[gidx];    float bfA[4]={t4.x,t4.y,t4.z,t4.w};
    t4 = ((const float4*)Wo)[gidx];    float w3[4] ={t4.x,t4.y,t4.z,t4.w};
    t4 = ((const float4*)tv_ws)[gidx]; float tvA[4]={t4.x,t4.y,t4.z,t4.w};
    const float bo0    = bo[gidx];
    const float bb     = betap[gidx];
    const float dS_sum = dsum[gidx];

    float4 zv = *((const float4*)(z + b*NIN + gidx*4));
    float zz[4]={zv.x,zv.y,zv.z,zv.w};

    // forward
    float x[4], xp[4], u1[4];
    #pragma unroll
    for (int i=0;i<4;i++){
        float a = bxA[i] + wx[i*4]*zz[0]+wx[i*4+1]*zz[1]+wx[i*4+2]*zz[2]+wx[i*4+3]*zz[3];
        x[i] = ftanh(a); xp[i] = 1.0f - x[i]*x[i];
        u1[i] = x[i] + tvA[i];
    }
    float h[4], hp[4];
    float a3 = bo0;
    #pragma unroll
    for (int i=0;i<4;i++){
        float a = bfA[i] + wf[i*4]*u1[0]+wf[i*4+1]*u1[1]+wf[i*4+2]*u1[2]+wf[i*4+3]*u1[3];
        h[i] = ftanh(a); hp[i] = 1.0f - h[i]*h[i];
        a3 += w3[i]*h[i];
    }
    float S = ftanh(a3), sp = 1.0f - S*S;

    // B[i,n] = sum_k Wf[i,k] * xp_k * Wx[k,n]
    float Bm[16];
    #pragma unroll
    for (int i=0;i<4;i++){
        #pragma unroll
        for (int n=0;n<4;n++){
            float s = 0.0f;
            #pragma unroll
            for (int k=0;k<4;k++) s += wf[i*4+k]*xp[k]*wx[k*4+n];
            Bm[i*4+n]=s;
        }
    }
    float w3hp[4], v[4];
    #pragma unroll
    for (int i=0;i<4;i++){ w3hp[i]=w3[i]*hp[i]; v[i]=sp*w3hp[i]; }
    float q[4]={0.f,0.f,0.f,0.f};
    #pragma unroll
    for (int i=0;i<4;i++){
        #pragma unroll
        for (int j=0;j<4;j++) q[j] += v[i]*wf[i*4+j];
    }
    float c[4];
    #pragma unroll
    for (int n=0;n<4;n++){
        float s=0.0f;
        #pragma unroll
        for (int i=0;i<4;i++) s += w3hp[i]*Bm[i*4+n];
        c[n]=s;
    }
    const float alpha = -2.0f*S*sp;
    float bet[4], gam[4];
    #pragma unroll
    for (int i=0;i<4;i++){ bet[i] = -2.0f*h[i]*v[i]; gam[i] = -2.0f*x[i]*xp[i]*q[i]; }

    // rho / nlp / dpp
    float rho[4], nlp[4], dpp[4];
    #pragma unroll
    for (int j=0;j<4;j++){
        float zj = zz[j];
        float xs = zj > 10.0f ? zj+100.0f : zj;
        xs = xs < -10.0f ? xs-100.0f : xs;
        float xn = (xs-mu)*inv_sig;
        float dens = __expf(-0.5f*xn*xn)*INV_SQRT_2PI;
        dens = (xn > 10.0f || xn < -10.0f) ? 0.0f : dens;
        rho[j] = dens*invZ + 1e-10f;
        nlp[j] = -(zj-mu)*inv_sig2;
        float d = zj-mu;
        dpp[j] = (d*d - sigma*sigma)*inv_s4;
    }
    float u_val = S - bb*__logf(rho[0]*rho[1]*rho[2]*rho[3]);

    // contractions with H = alpha c c^T + sum_i bet_i B_i B_i^T + sum_k gam_k A_k A_k^T
    float rc=0.0f, scs=0.0f;
    #pragma unroll
    for (int j=0;j<4;j++){ rc += rho[j]*c[j]; scs += c[j]; }
    float rB[4], sB[4], rA[4], sA[4];
    #pragma unroll
    for (int i=0;i<4;i++){
        float r=0.0f, s=0.0f, r2=0.0f, s2=0.0f;
        #pragma unroll
        for (int j=0;j<4;j++){
            r  += rho[j]*Bm[i*4+j]; s  += Bm[i*4+j];
            r2 += rho[j]*wx[i*4+j]; s2 += wx[i*4+j];
        }
        rB[i]=r; sB[i]=s; rA[i]=r2; sA[i]=s2;
    }

    float pde[4], uz[4], uzz[4];
    #pragma unroll
    for (int k=0;k<4;k++){
        float corr = alpha*rc*c[k];
        float hsum = alpha*scs*c[k];
        #pragma unroll
        for (int i=0;i<4;i++){
            corr += bet[i]*rB[i]*Bm[i*4+k];
            hsum += bet[i]*sB[i]*Bm[i*4+k];
            corr += gam[i]*rA[i]*wx[i*4+k];
            hsum += gam[i]*sA[i]*wx[i*4+k];
        }
        float uzk = sp*c[k] - bb*nlp[k];
        float utk = dS_sum + bb*corr*frcp(rho[k]+1e-5f);
        uz[k]  = uzk;
        uzz[k] = hsum - bb*dlp;
        pde[k] = utk + 0.5f*uzk*uzk + 0.125f*bb*bb*(nlp[k]*nlp[k] - 2.0f*dpp[k]);
    }

    const int base = b*NIN + gidx*4;
    *((float4*)(out + base))        = make_float4(pde[0],pde[1],pde[2],pde[3]);
    *((float4*)(out + OFF1 + base)) = make_float4(uz[0],uz[1],uz[2],uz[3]);
    out[OFF2 + b*NG + gidx] = u_val;
    *((float4*)(out + OFF3 + base)) = make_float4(uzz[0],uzz[1],uzz[2],uzz[3]);
}

extern "C" void kernel_launch(void* const* d_in, const int* in_sizes, int n_in,
                              void* d_out, int out_size, void* d_ws, size_t ws_size,
                              hipStream_t stream){
    (void)in_sizes; (void)n_in; (void)out_size; (void)ws_size;
    const float* z     = (const float*)d_in[0];
    const float* ts    = (const float*)d_in[1];
    const float* mu    = (const float*)d_in[2];
    const float* sigma = (const float*)d_in[3];
    const float* Wx    = (const float*)d_in[4];
    const float* bx    = (const float*)d_in[5];
    const float* Wt    = (const float*)d_in[6];
    const float* bt    = (const float*)d_in[7];
    const float* Wt2   = (const float*)d_in[8];
    const float* bt2   = (const float*)d_in[9];
    const float* Wf    = (const float*)d_in[10];
    const float* bf    = (const float*)d_in[11];
    const float* Wo    = (const float*)d_in[12];
    const float* bo    = (const float*)d_in[13];
    const float* beta  = (const float*)d_in[14];
    float* out = (float*)d_out;

    float* ws      = (float*)d_ws;
    float* tv_ws   = ws;            // 512
    float* dtv_ws  = ws + 512;      // 512
    float* consts  = ws + 1024;     // 8
    float* dsum    = ws + 1032;     // 128
    float* partial = ws + 1160;     // 2048*128 = 262144 (1 MB)

    k_pre <<<1,   128, 0, stream>>>(ts, mu, sigma, Wt, bt, Wt2, bt2, tv_ws, dtv_ws, consts);
    k_dsdt<<<2048,256, 0, stream>>>(z, Wx, bx, Wf, bf, Wo, bo, tv_ws, dtv_ws, partial);
    k_red <<<128, 256, 0, stream>>>(partial, dsum);
    k_main<<<4096,256, 0, stream>>>(z, Wx, bx, Wf, bf, Wo, bo, beta, tv_ws, consts, dsum, out);
}